// Round 1
// baseline (922.845 us; speedup 1.0000x reference)
//
#include <hip/hip_runtime.h>
#include <stdint.h>

#define B_ROWS 1024
#define H_DIM  768
#define N_ROWS 100000
#define C_DIM  42
#define NB     64
#define NCHUNK ((N_ROWS + NB - 1) / NB)   // 1563
#define K2_BLOCKS 782
#define K2_THREADS 512

typedef __attribute__((ext_vector_type(8))) short short8;
typedef __attribute__((ext_vector_type(4))) float f32x4;

__device__ __forceinline__ unsigned short f2bf(float f) {
    union { float f; unsigned u; } x; x.f = f;
    unsigned r = x.u + 0x7FFFu + ((x.u >> 16) & 1u);
    return (unsigned short)(r >> 16);
}

// orderable pack: value (monotone-mapped) in high 32, ~index low 32 (first-index tie-break)
__device__ __forceinline__ unsigned long long packvi(float v, unsigned n) {
    unsigned u = __float_as_uint(v);
    u = (u & 0x80000000u) ? ~u : (u | 0x80000000u);
    return ((unsigned long long)u << 32) | (unsigned long long)(~n);
}

// ---------------- K1: weak_data f32 -> bf16 A ----------------
__global__ void k_convA(const float* __restrict__ wd, unsigned short* __restrict__ A) {
    int idx = blockIdx.x * 256 + threadIdx.x;     // 768*256 = 196608 = 1024*768/4
    float4 v = reinterpret_cast<const float4*>(wd)[idx];
    union { unsigned short s[4]; uint2 u; } o;
    o.s[0] = f2bf(v.x); o.s[1] = f2bf(v.y); o.s[2] = f2bf(v.z); o.s[3] = f2bf(v.w);
    reinterpret_cast<uint2*>(A)[idx] = o.u;
}

// ---------------- K2: chunked GEMM + fused per-b argmax over chunk ----------------
__global__ __launch_bounds__(512, 2) void k_simmax(
    const float* __restrict__ mem,            // [N, 768] f32
    const unsigned short* __restrict__ A,     // [1024, 768] bf16
    unsigned long long* __restrict__ partial) // [NCHUNK][1024]
{
    __shared__ __align__(16) char ldsB[NB * 1536];  // 96 KB, bf16 rows, XOR-swizzled
    __shared__ float ldsN[NB];

    const int t    = threadIdx.x;
    const int lane = t & 63;
    const int wv   = t >> 6;          // 0..7
    const int fr   = lane & 15;       // fragment row/col index
    const int kgrp = lane >> 4;       // 0..3

    for (int ci = 0; ci < 2; ++ci) {
        const int c = blockIdx.x + ci * K2_BLOCKS;
        if (c >= NCHUNK) break;
        if (ci) __syncthreads();      // LDS reuse barrier

        // ---- stage chunk: 64 rows x 768 f32 -> bf16 LDS, compute inv norms ----
        {
            const int r  = t >> 3;          // 0..63 local row
            const int cb = (t & 7) * 4;     // col base
            const int n  = c * NB + r;
            const bool valid = (n < N_ROWS);
            const float* src = mem + (long long)n * H_DIM + cb;
            char* dst = ldsB + r * 1536;
            const int sw = (r & 7) << 4;
            float ss = 0.f;
            #pragma unroll
            for (int i = 0; i < 24; ++i) {
                float4 v;
                if (valid) v = *reinterpret_cast<const float4*>(src + i * 32);
                else       v = make_float4(0.f, 0.f, 0.f, 0.f);
                ss += v.x*v.x + v.y*v.y + v.z*v.z + v.w*v.w;
                union { unsigned short s[4]; uint2 u; } o;
                o.s[0]=f2bf(v.x); o.s[1]=f2bf(v.y); o.s[2]=f2bf(v.z); o.s[3]=f2bf(v.w);
                int off = (cb + i * 32) * 2;
                *reinterpret_cast<uint2*>(dst + (off ^ sw)) = o.u;
            }
            ss += __shfl_xor(ss, 1);
            ss += __shfl_xor(ss, 2);
            ss += __shfl_xor(ss, 4);
            if ((t & 7) == 0)
                ldsN[r] = valid ? (1.0f / fmaxf(sqrtf(ss), 1e-8f)) : 0.0f;
        }
        __syncthreads();

        float invn[4];
        #pragma unroll
        for (int nt = 0; nt < 4; ++nt) invn[nt] = ldsN[nt * 16 + fr];

        // ---- loop over all 1024 b rows: wave owns two 64-row b-groups ----
        #pragma unroll
        for (int gi = 0; gi < 2; ++gi) {
            const int b0 = (wv + 8 * gi) * 64;
            f32x4 acc[4][4];
            #pragma unroll
            for (int m = 0; m < 4; ++m)
                #pragma unroll
                for (int n = 0; n < 4; ++n)
                    acc[m][n] = (f32x4){0.f, 0.f, 0.f, 0.f};

            #pragma unroll 4
            for (int k = 0; k < 24; ++k) {
                const int k0 = k * 32 + kgrp * 8;
                short8 af[4], bf[4];
                #pragma unroll
                for (int m = 0; m < 4; ++m) {
                    const unsigned short* ap = A + (b0 + m * 16 + fr) * H_DIM + k0;
                    af[m] = *reinterpret_cast<const short8*>(ap);
                }
                #pragma unroll
                for (int n = 0; n < 4; ++n) {
                    int roww = n * 16 + fr;
                    int off  = roww * 1536 + k0 * 2;
                    off ^= (roww & 7) << 4;
                    bf[n] = *reinterpret_cast<const short8*>(ldsB + off);
                }
                #pragma unroll
                for (int m = 0; m < 4; ++m)
                    #pragma unroll
                    for (int n = 0; n < 4; ++n)
                        acc[m][n] = __builtin_amdgcn_mfma_f32_16x16x32_bf16(af[m], bf[n], acc[m][n], 0, 0, 0);
            }

            // ---- per-b argmax over this chunk's 64 n ----
            #pragma unroll
            for (int m = 0; m < 4; ++m) {
                #pragma unroll
                for (int r = 0; r < 4; ++r) {
                    unsigned long long best = 0ull;
                    #pragma unroll
                    for (int nt = 0; nt < 4; ++nt) {
                        unsigned nglob = (unsigned)(c * NB + nt * 16 + fr);
                        float v = acc[m][nt][r] * invn[nt];
                        unsigned long long p = (nglob < N_ROWS) ? packvi(v, nglob) : 0ull;
                        best = (p > best) ? p : best;
                    }
                    #pragma unroll
                    for (int s = 1; s < 16; s <<= 1) {
                        unsigned long long o = __shfl_xor(best, s);
                        best = (o > best) ? o : best;
                    }
                    if (fr == 0) {
                        int brow = b0 + m * 16 + kgrp * 4 + r;
                        partial[(long long)c * 1024 + brow] = best;
                    }
                }
            }
        }
    }
}

// ---------------- K3: reduce partials per b, gather + epilogue ----------------
__global__ void k_final(const unsigned long long* __restrict__ partial,
                        const float* __restrict__ wlog,
                        const float* __restrict__ llog,
                        float* __restrict__ out)
{
    __shared__ unsigned long long red[16][17];
    __shared__ int sidx[16];
    const int t  = threadIdx.x;
    const int b0 = blockIdx.x * 16;
    const int i  = t >> 4, j = t & 15;

    unsigned long long best = 0ull;
    for (int c = j; c < NCHUNK; c += 16) {
        unsigned long long p = partial[(long long)c * 1024 + b0 + i];
        best = (p > best) ? p : best;
    }
    red[i][j] = best;
    __syncthreads();
    if (t < 16) {
        unsigned long long m = red[t][0];
        #pragma unroll
        for (int jj = 1; jj < 16; ++jj) { unsigned long long p = red[t][jj]; m = (p > m) ? p : m; }
        sidx[t] = (int)(~(unsigned)(m & 0xFFFFFFFFull));
    }
    __syncthreads();
    for (int e = t; e < 16 * C_DIM; e += 256) {
        int bi = e / C_DIM, cc = e % C_DIM;
        int b  = b0 + bi;
        out[b * C_DIM + cc] = 0.7f * llog[(long long)sidx[bi] * C_DIM + cc]
                            - 99999.0f * wlog[b * C_DIM + cc];
    }
}

extern "C" void kernel_launch(void* const* d_in, const int* in_sizes, int n_in,
                              void* d_out, int out_size, void* d_ws, size_t ws_size,
                              hipStream_t stream) {
    const float* weak_data   = (const float*)d_in[0];
    const float* weak_logits = (const float*)d_in[1];
    const float* mem         = (const float*)d_in[2];
    const float* llog        = (const float*)d_in[3];
    float* out = (float*)d_out;

    unsigned short*     A       = (unsigned short*)d_ws;
    unsigned long long* partial = (unsigned long long*)((char*)d_ws + (2u << 20));

    k_convA <<<768, 256, 0, stream>>>(weak_data, A);
    k_simmax<<<K2_BLOCKS, K2_THREADS, 0, stream>>>(mem, A, partial);
    k_final <<<64, 256, 0, stream>>>(partial, weak_logits, llog, out);
}

// Round 2
// 901.620 us; speedup vs baseline: 1.0235x; 1.0235x over previous
//
#include <hip/hip_runtime.h>
#include <stdint.h>

#define B_ROWS 1024
#define H_DIM  768
#define N_ROWS 100000
#define C_DIM  42
#define NB     32
#define NCHUNK (N_ROWS / NB)      // 3125, exact (no tail)
#define GX     384                 // chunk-group blocks per b-half; grid = GX x 2 = 768 = 3/CU

typedef __attribute__((ext_vector_type(8))) short short8;
typedef __attribute__((ext_vector_type(4))) float f32x4;

__device__ __forceinline__ unsigned short f2bf(float f) {
    union { float f; unsigned u; } x; x.f = f;
    unsigned r = x.u + 0x7FFFu + ((x.u >> 16) & 1u);
    return (unsigned short)(r >> 16);
}

// orderable pack: monotone-mapped float in high 32, ~index low 32 (smaller n wins ties)
__device__ __forceinline__ unsigned long long packvi(float v, unsigned n) {
    unsigned u = __float_as_uint(v);
    u = (u & 0x80000000u) ? ~u : (u | 0x80000000u);
    return ((unsigned long long)u << 32) | (unsigned long long)(~n);
}

// ---------------- K1: weak_data f32 -> fragment-packed bf16 A2 ----------------
// A2 layout: A[row][col] stored at byte ((row>>4)*96 + (col>>3))*256 + (row&15)*16 + (col&7)*2
// so a wave's 16x8 MFMA A-fragment (rows rg*16+fr, cols kq*8+j) is one contiguous 1KB block,
// lane-linear at lane*16.
__global__ void k_convA(const float* __restrict__ wd, unsigned short* __restrict__ A2,
                        unsigned int* __restrict__ counters) {
    if (blockIdx.x == 0 && threadIdx.x == 0) { counters[0] = 0; counters[1] = 0; }
    int idx = blockIdx.x * 256 + threadIdx.x;     // over 1024*192 float4s
    int row = idx / 192;
    int c4  = idx - row * 192;
    int col = c4 * 4;
    float4 v = reinterpret_cast<const float4*>(wd)[idx];
    union { unsigned short s[4]; uint2 u; } o;
    o.s[0] = f2bf(v.x); o.s[1] = f2bf(v.y); o.s[2] = f2bf(v.z); o.s[3] = f2bf(v.w);
    size_t byte = (size_t)(((row >> 4) * 96 + (col >> 3)) * 256 + (row & 15) * 16 + (col & 7) * 2);
    *reinterpret_cast<uint2*>((char*)A2 + byte) = o.u;
}

// ---------------- K2: chunked GEMM + per-lane running argmax ----------------
__global__ __launch_bounds__(256, 3) void k_simmax(
    const float* __restrict__ mem,            // [N, 768] f32
    const unsigned short* __restrict__ A2,    // fragment-packed bf16
    unsigned int* __restrict__ counters,      // [2]
    unsigned long long* __restrict__ partial) // [2][GX][512]
{
    __shared__ __align__(16) char ldsB[NB * 1536];  // 48 KB bf16, XOR-swizzled rows
    __shared__ float ldsN[NB];
    __shared__ int s_c;

    const int t    = threadIdx.x;
    const int lane = t & 63;
    const int wv   = t >> 6;          // 0..3
    const int fr   = lane & 15;
    const int kgrp = lane >> 4;       // 0..3
    const int y    = blockIdx.y;      // b-half

    float    bv[2][4][4];
    unsigned bi[2][4][4];
    #pragma unroll
    for (int gi = 0; gi < 2; ++gi)
        #pragma unroll
        for (int m = 0; m < 4; ++m)
            #pragma unroll
            for (int r = 0; r < 4; ++r) { bv[gi][m][r] = -1e30f; bi[gi][m][r] = 0u; }

    const char* A2c = (const char*)A2 + (size_t)lane * 16;

    while (true) {
        __syncthreads();              // previous compute done before re-stage / s_c reuse
        if (t == 0) s_c = (int)atomicAdd(&counters[y], 1u);
        __syncthreads();
        const int c = s_c;
        if (c >= NCHUNK) break;

        // ---- stage chunk: 32 rows x 768 f32 -> bf16 LDS + inv norms ----
        {
            const int r  = t >> 3;          // 0..31
            const int j  = t & 7;
            const float* src = mem + (c * NB + r) * H_DIM + j * 4;
            char* dst = ldsB + r * 1536;
            const int sw = (r & 7) << 4;
            float ss = 0.f;
            #pragma unroll
            for (int i = 0; i < 24; ++i) {
                float4 v = *reinterpret_cast<const float4*>(src + i * 32);
                ss += v.x*v.x + v.y*v.y + v.z*v.z + v.w*v.w;
                union { unsigned short s[4]; uint2 u; } o;
                o.s[0]=f2bf(v.x); o.s[1]=f2bf(v.y); o.s[2]=f2bf(v.z); o.s[3]=f2bf(v.w);
                *reinterpret_cast<uint2*>(dst + ((j * 8 + i * 64) ^ sw)) = o.u;
            }
            ss += __shfl_xor(ss, 1);
            ss += __shfl_xor(ss, 2);
            ss += __shfl_xor(ss, 4);
            if (j == 0) ldsN[r] = 1.0f / fmaxf(sqrtf(ss), 1e-8f);
        }
        __syncthreads();

        const float invn[2] = { ldsN[fr], ldsN[16 + fr] };

        #pragma unroll
        for (int gi = 0; gi < 2; ++gi) {
            const int rg0 = y * 32 + gi * 16 + wv * 4;   // row-group base (b = rg0*16)
            const char* ap = A2c + (size_t)rg0 * 24576;
            f32x4 acc[4][2];
            #pragma unroll
            for (int m = 0; m < 4; ++m)
                #pragma unroll
                for (int nt = 0; nt < 2; ++nt)
                    acc[m][nt] = (f32x4){0.f, 0.f, 0.f, 0.f};

            #pragma unroll 6
            for (int k = 0; k < 24; ++k) {
                short8 af[4], bfr[2];
                #pragma unroll
                for (int m = 0; m < 4; ++m)
                    af[m] = *reinterpret_cast<const short8*>(ap + m * 24576 + k * 1024);
                #pragma unroll
                for (int nt = 0; nt < 2; ++nt) {
                    int roww = nt * 16 + fr;
                    int off  = (roww * 1536 + k * 64 + kgrp * 16) ^ ((roww & 7) << 4);
                    bfr[nt] = *reinterpret_cast<const short8*>(ldsB + off);
                }
                #pragma unroll
                for (int m = 0; m < 4; ++m)
                    #pragma unroll
                    for (int nt = 0; nt < 2; ++nt)
                        acc[m][nt] = __builtin_amdgcn_mfma_f32_16x16x32_bf16(af[m], bfr[nt], acc[m][nt], 0, 0, 0);
            }

            // per-lane running argmax (ascending n; strict > keeps first index)
            const unsigned nb0 = (unsigned)(c * NB) + (unsigned)fr;
            #pragma unroll
            for (int nt = 0; nt < 2; ++nt) {
                const unsigned nv = nb0 + nt * 16;
                #pragma unroll
                for (int m = 0; m < 4; ++m)
                    #pragma unroll
                    for (int r = 0; r < 4; ++r) {
                        float v = acc[m][nt][r] * invn[nt];
                        bool p = v > bv[gi][m][r];
                        bv[gi][m][r] = p ? v : bv[gi][m][r];
                        bi[gi][m][r] = p ? nv : bi[gi][m][r];
                    }
            }
        }
    }

    // ---- once per block: cross-lane (fr) reduce, write partial ----
    #pragma unroll
    for (int gi = 0; gi < 2; ++gi)
        #pragma unroll
        for (int m = 0; m < 4; ++m)
            #pragma unroll
            for (int r = 0; r < 4; ++r) {
                unsigned long long P = packvi(bv[gi][m][r], bi[gi][m][r]);
                #pragma unroll
                for (int s = 1; s < 16; s <<= 1) {
                    unsigned long long o = __shfl_xor(P, s);
                    P = (o > P) ? o : P;
                }
                if (fr == 0) {
                    int lb = gi * 256 + wv * 64 + m * 16 + kgrp * 4 + r;
                    partial[((size_t)y * GX + blockIdx.x) * 512 + lb] = P;
                }
            }
}

// ---------------- K3: reduce partials per b, gather + epilogue ----------------
__global__ void k_final(const unsigned long long* __restrict__ partial,
                        const float* __restrict__ wlog,
                        const float* __restrict__ llog,
                        float* __restrict__ out)
{
    __shared__ int sidx[16];
    const int t  = threadIdx.x;
    const int b0 = blockIdx.x * 16;
    const int i  = t >> 4, j = t & 15;

    const int b  = b0 + i;
    const int yy = b >> 9;
    const int lb = b & 511;

    unsigned long long P = 0ull;
    for (int g = j; g < GX; g += 16) {
        unsigned long long p = partial[((size_t)yy * GX + g) * 512 + lb];
        P = (p > P) ? p : P;
    }
    #pragma unroll
    for (int s = 1; s < 16; s <<= 1) {
        unsigned long long o = __shfl_xor(P, s);
        P = (o > P) ? o : P;
    }
    if (j == 0) sidx[i] = (int)(~(unsigned)(P & 0xFFFFFFFFull));
    __syncthreads();

    for (int e = t; e < 16 * C_DIM; e += 256) {
        int bi_ = e / C_DIM, cc = e - bi_ * C_DIM;
        int bb  = b0 + bi_;
        out[bb * C_DIM + cc] = 0.7f * llog[(size_t)sidx[bi_] * C_DIM + cc]
                             - 99999.0f * wlog[bb * C_DIM + cc];
    }
}

extern "C" void kernel_launch(void* const* d_in, const int* in_sizes, int n_in,
                              void* d_out, int out_size, void* d_ws, size_t ws_size,
                              hipStream_t stream) {
    const float* weak_data   = (const float*)d_in[0];
    const float* weak_logits = (const float*)d_in[1];
    const float* mem         = (const float*)d_in[2];
    const float* llog        = (const float*)d_in[3];
    float* out = (float*)d_out;

    unsigned short*     A2       = (unsigned short*)d_ws;                        // 1.5 MB
    unsigned int*       counters = (unsigned int*)((char*)d_ws + 0x180000);      // @1.5 MB
    unsigned long long* partial  = (unsigned long long*)((char*)d_ws + 0x200000);// @2 MB, 3 MB

    k_convA <<<768, 256, 0, stream>>>(weak_data, A2, counters);
    k_simmax<<<dim3(GX, 2), 256, 0, stream>>>(mem, A2, counters, partial);
    k_final <<<64, 256, 0, stream>>>(partial, weak_logits, llog, out);
}